// Round 21
// baseline (520.116 us; speedup 1.0000x reference)
//
#include <hip/hip_runtime.h>

typedef __bf16 bf16_t;
typedef __bf16 bf16x8 __attribute__((ext_vector_type(8)));
typedef float f32x4 __attribute__((ext_vector_type(4)));
typedef unsigned long long u64;

#define TSEQ 30
#define ISZ  100
#define HSZ  256
#define NB   5120        // LSTM batch
#define BATCH 512
#define G4   1024        // 4*H
#define TILE 320         // batch cols per block
#define NBGRP 16
#define CH   10240       // elements per K=32 chunk panel: 20 nblk * 512
#define SLABX (4 * CH)   // x slab per (bgrp,t): K=128
#define SLABH (8 * CH)   // h slab per (dir,bgrp): K=256

__device__ __forceinline__ float fsig(float x)  { return 1.0f / (1.0f + __expf(-x)); }
__device__ __forceinline__ float ftanh(float x) { return 2.0f / (1.0f + __expf(-2.0f * x)) - 1.0f; }

// ---- prep: weights -> MFMA-fragment layout, fold biases ------------------
__global__ void prep_weights(const float* __restrict__ Wih_f, const float* __restrict__ Whh_f,
                             const float* __restrict__ bih_f, const float* __restrict__ bhh_f,
                             const float* __restrict__ Wih_b, const float* __restrict__ Whh_b,
                             const float* __restrict__ bih_b, const float* __restrict__ bhh_b,
                             bf16_t* __restrict__ Wf, float* __restrict__ bias)
{
    int idx = blockIdx.x * 256 + threadIdx.x;          // over 2*1024*384
    if (idx >= 2 * G4 * 384) return;
    int d = idx / (G4 * 384);
    int r = (idx / 384) % G4;
    int k = idx % 384;
    int h = r >> 2, gate = r & 3;
    int grow = gate * HSZ + h;
    const float* Wih = d ? Wih_b : Wih_f;
    const float* Whh = d ? Whh_b : Whh_f;
    float v;
    if (k < ISZ)       v = Wih[grow * ISZ + k];
    else if (k < 128)  v = 0.0f;
    else               v = Whh[grow * HSZ + (k - 128)];
    int mf = r >> 4, lr = r & 15;
    int ks = k >> 5, lq = (k >> 3) & 3, e = k & 7;
    size_t o = ((((size_t)d * 64 + mf) * 12 + ks) * 64 + lq * 16 + lr) * 8 + e;
    Wf[o] = (bf16_t)v;
    if (k == 0) {
        const float* bih = d ? bih_b : bih_f;
        const float* bhh = d ? bhh_b : bhh_f;
        bias[d * G4 + r] = bih[grow] + bhh[grow];
    }
}

// ---- prep: x -> fragment layout, chunk-contiguous ------------------------
__global__ void prep_x(const float* __restrict__ x, bf16_t* __restrict__ xBf)
{
    int idx = blockIdx.x * 256 + threadIdx.x;          // over 16*30*4*20*512
    if (idx >= NBGRP * TSEQ * SLABX) return;
    int e    = idx & 7;
    int lane = (idx >> 3) & 63;
    int i2   = idx >> 9;
    int nblk = i2 % 20; i2 /= 20;
    int ks   = i2 & 3;  i2 >>= 2;
    int t    = i2 % TSEQ;
    int bgrp = i2 / TSEQ;
    int n = bgrp * TILE + nblk * 16 + (lane & 15);
    int k = ks * 32 + (lane >> 4) * 8 + e;
    float v = (k < ISZ) ? x[(size_t)n * (TSEQ * ISZ) + t * ISZ + k] : 0.0f;
    xBf[idx] = (bf16_t)v;
}

// ---- prep: h0 -> fragment layout ping buffer -----------------------------
__global__ void prep_state(const float* __restrict__ h0, bf16_t* __restrict__ hA)
{
    int idx = blockIdx.x * 256 + threadIdx.x;          // over 2*16*8*20*512
    if (idx >= 2 * NBGRP * SLABH) return;
    int e    = idx & 7;
    int lane = (idx >> 3) & 63;
    int i2   = idx >> 9;
    int nblk = i2 % 20; i2 /= 20;
    int ksh  = i2 & 7;  i2 >>= 3;
    int bgrp = i2 & 15;
    int dir  = i2 >> 4;
    int col = bgrp * TILE + nblk * 16 + (lane & 15);
    int hid = ksh * 32 + (lane >> 4) * 8 + e;
    hA[idx] = (bf16_t)h0[((size_t)dir * NB + col) * HSZ + hid];
}

// ---- prep: c0 -> per-thread-contiguous layout (512-block geometry) -------
// cws[(bid*512+tid)*10 + m*5 + nf]; bid = dir*256 + msub*16 + bgrp
__global__ void prep_c(const float* __restrict__ c0, float* __restrict__ cws)
{
    int idx = blockIdx.x * 256 + threadIdx.x;          // over 512*512*10
    if (idx >= 512 * 512 * 10) return;
    int cell = idx % 10;
    int m  = cell / 5, nf = cell % 5;
    int tid = (idx / 10) & 511;
    int bid = idx / (10 * 512);
    int dir  = bid >> 8;
    int msub = (bid >> 4) & 15;
    int bgrp = bid & 15;
    int wave = tid >> 6, lane = tid & 63;
    int mw = wave >> 2, nw = wave & 3;
    int lr = lane & 15, lq = lane >> 4;
    int col = bgrp * TILE + nw * 80 + nf * 16 + lr;
    int hid = msub * 16 + mw * 8 + m * 4 + lq;
    cws[idx] = c0[((size_t)dir * NB + col) * HSZ + hid];
}

// ---- prep: transpose W1 for coalesced head ------------------------------
__global__ void prep_w1t(const float* __restrict__ W1, float* __restrict__ W1T)
{
    int idx = blockIdx.x * 256 + threadIdx.x;          // over 2560*64
    if (idx >= 2560 * 64) return;
    int k = idx / 64, j = idx % 64;
    W1T[k * 64 + j] = W1[j * 2560 + k];
}

// ---- the 30-step loop, templated on exchange path (r13 structure) --------
// Half-size block: 4 mf (64 gate rows), acc[2][5]. Everything else is the
// proven r13 flow: direct b loads, pkL pack, 2 syncthreads, monolithic
// group barrier (16 members now), L1 flash-inv on the fast path.
template<bool FAST>
__device__ void run_steps(const bf16_t* __restrict__ xBf,
                          bf16_t* __restrict__ hA, bf16_t* __restrict__ hB,
                          bf16_t* __restrict__ hfin,
                          const bf16_t* wL, bf16_t* pkL, unsigned* mybar,
                          float* cst, const float4* bq,
                          int dir, int bgrp, int msub,
                          int tid, int lane, int mw, int nw, int lr, int lq)
{
    const unsigned fo = (unsigned)(nw * 5 * 512 + lane * 8);

#pragma unroll 1
    for (int t = 0; t < TSEQ; ++t) {
        const bf16_t* hs = (t & 1) ? hB : hA;
        bf16_t*       hw = (t & 1) ? hA : hB;
        const int tx = dir ? (TSEQ - 1 - t) : t;
        const bf16_t* xsl = xBf + (size_t)(bgrp * TSEQ + tx) * SLABX + fo;
        const bf16_t* hsl = hs + (size_t)(dir * NBGRP + bgrp) * SLABH + fo;

        f32x4 acc[2][5] = {};
        // --- x chunks (K=0..127): plain L2-cached loads ---
#pragma unroll
        for (int c = 0; c < 4; ++c) {
            bf16x8 b[5];
#pragma unroll
            for (int nf = 0; nf < 5; ++nf)
                b[nf] = *(const bf16x8*)(xsl + (size_t)c * CH + nf * 512);
            bf16x8 a[2];
#pragma unroll
            for (int m = 0; m < 2; ++m)
                a[m] = *(const bf16x8*)(wL + ((mw * 2 + m) * 12 + c) * 512 + lane * 8);
#pragma unroll
            for (int m = 0; m < 2; ++m)
#pragma unroll
                for (int nf = 0; nf < 5; ++nf)
                    acc[m][nf] = __builtin_amdgcn_mfma_f32_16x16x32_bf16(a[m], b[nf], acc[m][nf], 0, 0, 0);
        }
        // --- h chunks (K=128..383) ---
#pragma unroll
        for (int c = 4; c < 12; ++c) {
            bf16x8 b[5];
#pragma unroll
            for (int nf = 0; nf < 5; ++nf) {
                const bf16_t* src = hsl + (size_t)(c - 4) * CH + nf * 512;
                if (FAST) {
                    b[nf] = *(const bf16x8*)src;       // local-XCD L2 hit
                } else {
                    union { u64 q[2]; bf16x8 v; } u;
                    u.q[0] = __hip_atomic_load((const u64*)src,       __ATOMIC_RELAXED, __HIP_MEMORY_SCOPE_AGENT);
                    u.q[1] = __hip_atomic_load((const u64*)(src + 4), __ATOMIC_RELAXED, __HIP_MEMORY_SCOPE_AGENT);
                    b[nf] = u.v;
                }
            }
            bf16x8 a[2];
#pragma unroll
            for (int m = 0; m < 2; ++m)
                a[m] = *(const bf16x8*)(wL + ((mw * 2 + m) * 12 + c) * 512 + lane * 8);
#pragma unroll
            for (int m = 0; m < 2; ++m)
#pragma unroll
                for (int nf = 0; nf < 5; ++nf)
                    acc[m][nf] = __builtin_amdgcn_mfma_f32_16x16x32_bf16(a[m], b[nf], acc[m][nf], 0, 0, 0);
        }

        // --- gates + state update ---
        if (t < TSEQ - 1) {
#pragma unroll
            for (int m = 0; m < 2; ++m) {
                float4 bb = bq[m];
#pragma unroll
                for (int nf = 0; nf < 5; ++nf) {
                    f32x4 g = acc[m][nf];
                    float gi = fsig(g[0] + bb.x);
                    float gf = fsig(g[1] + bb.y);
                    float gz = ftanh(g[2] + bb.z);
                    float go = fsig(g[3] + bb.w);
                    float cn = gf * cst[m * 5 + nf] + gi * gz;
                    cst[m * 5 + nf] = cn;
                    pkL[(nw * 5 + nf) * 256 + (mw * 16 + lr) * 8 + m * 4 + lq]
                        = (bf16_t)(go * ftanh(cn));
                }
            }
            __syncthreads();                           // pack complete
            // coalesced copy pkL (10KB) -> this block's 16-hid strip of slab
            bf16_t* dstb = hw + (size_t)(dir * NBGRP + bgrp) * SLABH;
            {
                int i = tid;                           // 512 thr cover 640 uint4 in 2 passes
                for (; i < 640; i += 512) {
                    int seg = i >> 5, off = i & 31;
                    uint4 v = *(const uint4*)(pkL + i * 8);
                    size_t eo = (size_t)(msub >> 1) * CH + seg * 512 + (msub & 1) * 256 + off * 8;
                    if (FAST) {
                        *(uint4*)(dstb + eo) = v;
                    } else {
                        union { uint4 q; u64 w[2]; } cv; cv.q = v;
                        __hip_atomic_store((u64*)(dstb + eo),     cv.w[0], __ATOMIC_RELAXED, __HIP_MEMORY_SCOPE_AGENT);
                        __hip_atomic_store((u64*)(dstb + eo + 4), cv.w[1], __ATOMIC_RELAXED, __HIP_MEMORY_SCOPE_AGENT);
                    }
                }
            }
            __syncthreads();                           // stores drained (vmcnt0 at barrier)
            if (tid == 0) {
                __hip_atomic_fetch_add(mybar, 1u,
                    FAST ? __ATOMIC_RELAXED : __ATOMIC_RELEASE, __HIP_MEMORY_SCOPE_AGENT);
                while (__hip_atomic_fetch_add(mybar, 0u, __ATOMIC_RELAXED, __HIP_MEMORY_SCOPE_AGENT)
                       < 16u * (unsigned)(t + 2))
                    __builtin_amdgcn_s_sleep(1);
            }
            __syncthreads();                           // whole block sees barrier passed
            if (FAST)                                  // flash-inv per-CU L1
                asm volatile("buffer_inv sc0" ::: "memory");
        } else {
            // final step: plain-layout hfin (kernel-boundary coherence for head)
#pragma unroll
            for (int m = 0; m < 2; ++m) {
                float4 bb = bq[m];
                int hid = msub * 16 + mw * 8 + m * 4 + lq;
#pragma unroll
                for (int nf = 0; nf < 5; ++nf) {
                    f32x4 g = acc[m][nf];
                    float gi = fsig(g[0] + bb.x);
                    float gf = fsig(g[1] + bb.y);
                    float gz = ftanh(g[2] + bb.z);
                    float go = fsig(g[3] + bb.w);
                    float cn = gf * cst[m * 5 + nf] + gi * gz;
                    float hn = go * ftanh(cn);
                    int col = bgrp * TILE + nw * 80 + nf * 16 + lr;
                    hfin[((size_t)dir * NB + col) * HSZ + hid] = (bf16_t)hn;
                }
            }
        }
    }
}

// ---- persistent LSTM: 512 blocks, 2/CU, dual independent chains per CU ---
// bid = dir*256 + msub*16 + bgrp. Under round-robin: (a) the 16 group
// members (fixed dir,bgrp) share bid%8 = bgrp%8 -> one XCD (runtime
// verified); (b) co-resident pair (bid, bid+256) = dir0/dir1 of the SAME
// (msub,bgrp) -> two INDEPENDENT chains per CU. When one chain parks at
// its barrier (s_sleep + s_barrier issue nothing), the other chain's 8
// waves own the CU -> the ~6µs/step exchange latency hides under real work.
// launch_bounds(512,4): 4 waves/EU = 2 blocks/CU, 128-reg cap (fits: ~116).
__global__ __launch_bounds__(512, 4)
void lstm_persist(const bf16_t* __restrict__ Wf, const float* __restrict__ bias,
                  const bf16_t* __restrict__ xBf, const float* __restrict__ cws,
                  bf16_t* __restrict__ hA, bf16_t* __restrict__ hB,
                  bf16_t* __restrict__ hfin, unsigned* __restrict__ bar,
                  unsigned* __restrict__ xccA)
{
    __shared__ __align__(16) bf16_t wL[4 * 12 * 512];  // 48KB W slice (4 mf)
    __shared__ __align__(16) bf16_t pkL[5120];         // 10KB h pack buffer
    __shared__ int sFast;

    const int bid  = blockIdx.x;
    const int dir  = bid >> 8;
    const int msub = (bid >> 4) & 15;
    const int bgrp = bid & 15;
    const int tid  = threadIdx.x;
    const int wave = tid >> 6;
    const int lane = tid & 63;
    const int mw   = wave >> 2;                        // 0..1 (2 mf each)
    const int nw   = wave & 3;                         // 0..3 (80 cols each)
    const int lr   = lane & 15;
    const int lq   = lane >> 4;

    // --- stage W slice once; c -> registers; bias -> registers ---
    {
        const uint4* wsrc = (const uint4*)(Wf + ((size_t)dir * 64 + msub * 4) * 12 * 512);
        uint4* wdst = (uint4*)wL;
        for (int i = tid; i < 3072; i += 512) wdst[i] = wsrc[i];
    }
    const float* cp = cws + ((size_t)bid * 512 + tid) * 10;
    float cst[10];
#pragma unroll
    for (int i = 0; i < 10; i += 2) {
        float2 v = *(const float2*)(cp + i);
        cst[i] = v.x; cst[i + 1] = v.y;
    }
    float4 bq[2];
#pragma unroll
    for (int m = 0; m < 2; ++m)
        bq[m] = *(const float4*)(bias + dir * G4 + (msub * 16 + mw * 8 + m * 4 + lq) * 4);

    unsigned* mybar = bar + (dir * NBGRP + bgrp) * 16; // 64B-spaced counters

    // --- publish XCD id, group-verify co-location (once, 16 members) ---
    unsigned xcc;
    asm volatile("s_getreg_b32 %0, hwreg(HW_REG_XCC_ID)" : "=s"(xcc));
    if (tid == 0) {
        __hip_atomic_store(&xccA[bid], xcc, __ATOMIC_RELAXED, __HIP_MEMORY_SCOPE_AGENT);
        __hip_atomic_fetch_add(mybar, 1u, __ATOMIC_RELEASE, __HIP_MEMORY_SCOPE_AGENT);
        while (__hip_atomic_fetch_add(mybar, 0u, __ATOMIC_RELAXED, __HIP_MEMORY_SCOPE_AGENT) < 16u)
            __builtin_amdgcn_s_sleep(1);
        int ok = (xcc < 8u) ? 1 : 0;
        for (int m2 = 0; m2 < 16; ++m2) {
            unsigned v = __hip_atomic_load(&xccA[dir * 256 + m2 * 16 + bgrp],
                                           __ATOMIC_RELAXED, __HIP_MEMORY_SCOPE_AGENT);
            ok &= (v == xcc) ? 1 : 0;
        }
        sFast = ok;
    }
    __syncthreads();

    if (sFast)
        run_steps<true>(xBf, hA, hB, hfin, wL, pkL, mybar, cst, bq,
                        dir, bgrp, msub, tid, lane, mw, nw, lr, lq);
    else
        run_steps<false>(xBf, hA, hB, hfin, wL, pkL, mybar, cst, bq,
                         dir, bgrp, msub, tid, lane, mw, nw, lr, lq);
}

// ---- head: x_fea assembly + Linear(2560,64) + Linear(64,5) + softmax ----
__global__ __launch_bounds__(256)
void head_kernel(const bf16_t* __restrict__ hfin, const float* __restrict__ W1T,
                 const float* __restrict__ b1, const float* __restrict__ W2,
                 const float* __restrict__ b2, float* __restrict__ out)
{
    __shared__ float flat_s[2560];
    __shared__ float partial[4][64];
    __shared__ float zs[64];
    __shared__ float ls[5];
    __shared__ float es[5];
    int b = blockIdx.x, tid = threadIdx.x;
    const bf16_t* hF = hfin;
    const bf16_t* hB = hfin + (size_t)NB * HSZ;
    float* xfea = out + BATCH * 5 + (size_t)b * 2560;

    for (int j = tid; j < 2560; j += 256) {
        int s = j >> 8, c = j & 255;
        int n = b * 10 + s;
        float v = (c < 128) ? (float)hF[(size_t)n * HSZ + c] : (float)hB[(size_t)n * HSZ + c];
        flat_s[j] = v;
        xfea[j] = v;
    }
    __syncthreads();
    int j = tid & 63, q = tid >> 6;
    float sum = 0.0f;
    for (int k = q * 640; k < (q + 1) * 640; ++k) sum += flat_s[k] * W1T[k * 64 + j];
    partial[q][j] = sum;
    __syncthreads();
    if (tid < 64) zs[tid] = partial[0][tid] + partial[1][tid] + partial[2][tid] + partial[3][tid] + b1[tid];
    __syncthreads();
    if (tid < 5) {
        float l = b2[tid];
        for (int k = 0; k < 64; ++k) l += zs[k] * W2[tid * 64 + k];
        ls[tid] = l;
    }
    __syncthreads();
    if (tid < 5) {
        float m = ls[0];
        for (int k = 1; k < 5; ++k) m = fmaxf(m, ls[k]);
        es[tid] = __expf(ls[tid] - m);
    }
    __syncthreads();
    if (tid < 5) {
        float s5 = es[0] + es[1] + es[2] + es[3] + es[4];
        out[b * 5 + tid] = es[tid] / s5;
    }
}

extern "C" void kernel_launch(void* const* d_in, const int* in_sizes, int n_in,
                              void* d_out, int out_size, void* d_ws, size_t ws_size,
                              hipStream_t stream) {
    const float* x     = (const float*)d_in[0];
    const float* h0    = (const float*)d_in[1];
    const float* c0    = (const float*)d_in[2];
    const float* Wih_f = (const float*)d_in[3];
    const float* Whh_f = (const float*)d_in[4];
    const float* bih_f = (const float*)d_in[5];
    const float* bhh_f = (const float*)d_in[6];
    const float* Wih_b = (const float*)d_in[7];
    const float* Whh_b = (const float*)d_in[8];
    const float* bih_b = (const float*)d_in[9];
    const float* bhh_b = (const float*)d_in[10];
    const float* W1    = (const float*)d_in[11];
    const float* b1    = (const float*)d_in[12];
    const float* W2    = (const float*)d_in[13];
    const float* b2    = (const float*)d_in[14];
    float* out = (float*)d_out;

    uintptr_t ws = (uintptr_t)d_ws;
    bf16_t*   Wf   = (bf16_t*)(ws);                    // 1,572,864
    float*    bias = (float*)(ws + 1572864);           // 8,192
    bf16_t*   xBf  = (bf16_t*)(ws + 1581056);          // 39,321,600
    bf16_t*   hAb  = (bf16_t*)(ws + 40902656);         // 5,242,880
    bf16_t*   hBb  = (bf16_t*)(ws + 46145536);         // 5,242,880
    bf16_t*   hfin = (bf16_t*)(ws + 51388416);         // 5,242,880
    float*    W1T  = (float*)(ws + 56631296);          // 655,360
    float*    cws  = (float*)(ws + 57286656);          // 10,485,760
    unsigned* bar  = (unsigned*)(ws + 67772416);       // 2,048 (32 groups x 64B)
    unsigned* xccA = (unsigned*)(ws + 67774464);       // 2,048 (512 u32)

    hipMemsetAsync((void*)bar, 0, 4096, stream);

    prep_weights<<<(2 * G4 * 384 + 255) / 256, 256, 0, stream>>>(
        Wih_f, Whh_f, bih_f, bhh_f, Wih_b, Whh_b, bih_b, bhh_b, Wf, bias);
    prep_x<<<(NBGRP * TSEQ * SLABX + 255) / 256, 256, 0, stream>>>(x, xBf);
    prep_state<<<(2 * NBGRP * SLABH + 255) / 256, 256, 0, stream>>>(h0, hAb);
    prep_c<<<(512 * 512 * 10 + 255) / 256, 256, 0, stream>>>(c0, cws);
    prep_w1t<<<(2560 * 64 + 255) / 256, 256, 0, stream>>>(W1, W1T);

    lstm_persist<<<512, 512, 0, stream>>>(Wf, bias, xBf, cws, hAb, hBb, hfin, bar, xccA);
    head_kernel<<<BATCH, 256, 0, stream>>>(hfin, W1T, b1, W2, b2, out);
}

// Round 22
// 446.794 us; speedup vs baseline: 1.1641x; 1.1641x over previous
//
#include <hip/hip_runtime.h>

typedef __bf16 bf16_t;
typedef __bf16 bf16x8 __attribute__((ext_vector_type(8)));
typedef float f32x4 __attribute__((ext_vector_type(4)));
typedef unsigned long long u64;

#define TSEQ 30
#define ISZ  100
#define HSZ  256
#define NB   5120        // LSTM batch
#define BATCH 512
#define G4   1024        // 4*H
#define TILE 320         // batch cols per block
#define NBGRP 16
#define CH   10240       // elements per K=32 chunk panel: 20 nblk * 512
#define SLABX (4 * CH)   // x slab per (bgrp,t): K=128
#define SLABH (8 * CH)   // h slab per (dir,bgrp): K=256

__device__ __forceinline__ float fsig(float x)  { return 1.0f / (1.0f + __expf(-x)); }
__device__ __forceinline__ float ftanh(float x) { return 2.0f / (1.0f + __expf(-2.0f * x)) - 1.0f; }

// ---- prep: weights -> MFMA-fragment layout, fold biases ------------------
__global__ void prep_weights(const float* __restrict__ Wih_f, const float* __restrict__ Whh_f,
                             const float* __restrict__ bih_f, const float* __restrict__ bhh_f,
                             const float* __restrict__ Wih_b, const float* __restrict__ Whh_b,
                             const float* __restrict__ bih_b, const float* __restrict__ bhh_b,
                             bf16_t* __restrict__ Wf, float* __restrict__ bias)
{
    int idx = blockIdx.x * 256 + threadIdx.x;          // over 2*1024*384
    if (idx >= 2 * G4 * 384) return;
    int d = idx / (G4 * 384);
    int r = (idx / 384) % G4;
    int k = idx % 384;
    int h = r >> 2, gate = r & 3;
    int grow = gate * HSZ + h;
    const float* Wih = d ? Wih_b : Wih_f;
    const float* Whh = d ? Whh_b : Whh_f;
    float v;
    if (k < ISZ)       v = Wih[grow * ISZ + k];
    else if (k < 128)  v = 0.0f;
    else               v = Whh[grow * HSZ + (k - 128)];
    int mf = r >> 4, lr = r & 15;
    int ks = k >> 5, lq = (k >> 3) & 3, e = k & 7;
    size_t o = ((((size_t)d * 64 + mf) * 12 + ks) * 64 + lq * 16 + lr) * 8 + e;
    Wf[o] = (bf16_t)v;
    if (k == 0) {
        const float* bih = d ? bih_b : bih_f;
        const float* bhh = d ? bhh_b : bhh_f;
        bias[d * G4 + r] = bih[grow] + bhh[grow];
    }
}

// ---- prep: x -> fragment layout, chunk-contiguous ------------------------
__global__ void prep_x(const float* __restrict__ x, bf16_t* __restrict__ xBf)
{
    int idx = blockIdx.x * 256 + threadIdx.x;          // over 16*30*4*20*512
    if (idx >= NBGRP * TSEQ * SLABX) return;
    int e    = idx & 7;
    int lane = (idx >> 3) & 63;
    int i2   = idx >> 9;
    int nblk = i2 % 20; i2 /= 20;
    int ks   = i2 & 3;  i2 >>= 2;
    int t    = i2 % TSEQ;
    int bgrp = i2 / TSEQ;
    int n = bgrp * TILE + nblk * 16 + (lane & 15);
    int k = ks * 32 + (lane >> 4) * 8 + e;
    float v = (k < ISZ) ? x[(size_t)n * (TSEQ * ISZ) + t * ISZ + k] : 0.0f;
    xBf[idx] = (bf16_t)v;
}

// ---- prep: h0 -> fragment layout ping buffer -----------------------------
__global__ void prep_state(const float* __restrict__ h0, bf16_t* __restrict__ hA)
{
    int idx = blockIdx.x * 256 + threadIdx.x;          // over 2*16*8*20*512
    if (idx >= 2 * NBGRP * SLABH) return;
    int e    = idx & 7;
    int lane = (idx >> 3) & 63;
    int i2   = idx >> 9;
    int nblk = i2 % 20; i2 /= 20;
    int ksh  = i2 & 7;  i2 >>= 3;
    int bgrp = i2 & 15;
    int dir  = i2 >> 4;
    int col = bgrp * TILE + nblk * 16 + (lane & 15);
    int hid = ksh * 32 + (lane >> 4) * 8 + e;
    hA[idx] = (bf16_t)h0[((size_t)dir * NB + col) * HSZ + hid];
}

// ---- prep: c0 -> per-thread-contiguous layout ----------------------------
__global__ void prep_c(const float* __restrict__ c0, float* __restrict__ cws)
{
    int idx = blockIdx.x * 256 + threadIdx.x;          // over 256*512*20
    if (idx >= 256 * 512 * 20) return;
    int m   = idx & 3;
    int nf  = (idx >> 2) % 5;
    int tid = (idx / 20) & 511;
    int bid = idx / (20 * 512);
    int msub = bid >> 5, dir = (bid >> 4) & 1, bgrp = bid & 15;
    int lane = tid & 63, mw = (tid >> 6) >> 2, nw = (tid >> 6) & 3;
    int lr = lane & 15, lq = lane >> 4;
    int col = bgrp * TILE + nw * 80 + nf * 16 + lr;
    int hid = msub * 32 + mw * 16 + m * 4 + lq;
    cws[idx] = c0[((size_t)dir * NB + col) * HSZ + hid];
}

// ---- prep: transpose W1 for coalesced head ------------------------------
__global__ void prep_w1t(const float* __restrict__ W1, float* __restrict__ W1T)
{
    int idx = blockIdx.x * 256 + threadIdx.x;          // over 2560*64
    if (idx >= 2560 * 64) return;
    int k = idx / 64, j = idx % 64;
    W1T[k * 64 + j] = W1[j * 2560 + k];
}

// ---- the 30-step loop, templated on exchange path ------------------------
// FAST (group verified co-XCD): plain h stores (dirty local L2), plain h
// loads (hit local L2), RELAXED RMW barrier, buffer_inv sc0 (L1-only) per
// step. SLOW (any mapping): r12-proven MALL-coherent 8B atomics + RELEASE.
// Both: B direct-to-register (fragment layout -> perfectly coalesced bf16x8
// loads), NO LDS staging of B, minimal barriers (2/step, epilogue only).
template<bool FAST>
__device__ void run_steps(const bf16_t* __restrict__ xBf,
                          bf16_t* __restrict__ hA, bf16_t* __restrict__ hB,
                          bf16_t* __restrict__ hfin,
                          const bf16_t* wL, bf16_t* pkL, unsigned* mybar,
                          f32x4* c4, const float4* bq,
                          int dir, int bgrp, int msub,
                          int tid, int lane, int mw, int nw, int lr, int lq)
{
#pragma unroll 1
    for (int t = 0; t < TSEQ; ++t) {
        const bf16_t* hs = (t & 1) ? hB : hA;
        bf16_t*       hw = (t & 1) ? hA : hB;
        const int tx = dir ? (TSEQ - 1 - t) : t;
        const bf16_t* xsl = xBf + (size_t)(bgrp * TSEQ + tx) * SLABX + nw * 5 * 512 + lane * 8;
        const bf16_t* hsl = hs + (size_t)(dir * NBGRP + bgrp) * SLABH + nw * 5 * 512 + lane * 8;

        f32x4 acc[4][5] = {};
        // --- x chunks (K=0..127): plain L2-cached loads ---
#pragma unroll
        for (int c = 0; c < 4; ++c) {
            bf16x8 b[5];
#pragma unroll
            for (int nf = 0; nf < 5; ++nf)
                b[nf] = *(const bf16x8*)(xsl + (size_t)c * CH + nf * 512);
            bf16x8 a[4];
#pragma unroll
            for (int m = 0; m < 4; ++m)
                a[m] = *(const bf16x8*)(wL + ((mw * 4 + m) * 12 + c) * 512 + lane * 8);
#pragma unroll
            for (int m = 0; m < 4; ++m)
#pragma unroll
                for (int nf = 0; nf < 5; ++nf)
                    acc[m][nf] = __builtin_amdgcn_mfma_f32_16x16x32_bf16(a[m], b[nf], acc[m][nf], 0, 0, 0);
        }
        // --- h chunks (K=128..383) ---
#pragma unroll
        for (int c = 4; c < 12; ++c) {
            bf16x8 b[5];
#pragma unroll
            for (int nf = 0; nf < 5; ++nf) {
                const bf16_t* src = hsl + (size_t)(c - 4) * CH + nf * 512;
                if (FAST) {
                    b[nf] = *(const bf16x8*)src;       // local-XCD L2 hit
                } else {
                    union { u64 q[2]; bf16x8 v; } u;
                    u.q[0] = __hip_atomic_load((const u64*)src,       __ATOMIC_RELAXED, __HIP_MEMORY_SCOPE_AGENT);
                    u.q[1] = __hip_atomic_load((const u64*)(src + 4), __ATOMIC_RELAXED, __HIP_MEMORY_SCOPE_AGENT);
                    b[nf] = u.v;
                }
            }
            bf16x8 a[4];
#pragma unroll
            for (int m = 0; m < 4; ++m)
                a[m] = *(const bf16x8*)(wL + ((mw * 4 + m) * 12 + c) * 512 + lane * 8);
#pragma unroll
            for (int m = 0; m < 4; ++m)
#pragma unroll
                for (int nf = 0; nf < 5; ++nf)
                    acc[m][nf] = __builtin_amdgcn_mfma_f32_16x16x32_bf16(a[m], b[nf], acc[m][nf], 0, 0, 0);
        }

        // --- gates + state update ---
        if (t < TSEQ - 1) {
#pragma unroll
            for (int m = 0; m < 4; ++m) {
                float4 bb = bq[m];
                int hl = mw * 16 + m * 4 + lq;
#pragma unroll
                for (int nf = 0; nf < 5; ++nf) {
                    f32x4 g = acc[m][nf];
                    float gi = fsig(g[0] + bb.x);
                    float gf = fsig(g[1] + bb.y);
                    float gz = ftanh(g[2] + bb.z);
                    float go = fsig(g[3] + bb.w);
                    float cn = gf * c4[nf][m] + gi * gz;
                    c4[nf][m] = cn;
                    pkL[(nw * 5 + nf) * 512 + ((hl >> 3) * 16 + lr) * 8 + (hl & 7)]
                        = (bf16_t)(go * ftanh(cn));
                }
            }
            __syncthreads();                           // pack complete
            bf16_t* dstb = hw + (size_t)(dir * NBGRP + bgrp) * SLABH + (size_t)msub * 20 * 512;
            if (FAST) {
                uint4* dst = (uint4*)dstb;
                const uint4* src = (const uint4*)pkL;
                for (int i = tid; i < 1280; i += 512) dst[i] = src[i];
            } else {
                u64* dst = (u64*)dstb;
                const u64* src = (const u64*)pkL;
                for (int i = tid; i < 2560; i += 512)
                    __hip_atomic_store(&dst[i], src[i], __ATOMIC_RELAXED, __HIP_MEMORY_SCOPE_AGENT);
            }
            __syncthreads();                           // stores drained (vmcnt0 at barrier)
            if (tid == 0) {
                __hip_atomic_fetch_add(mybar, 1u,
                    FAST ? __ATOMIC_RELAXED : __ATOMIC_RELEASE, __HIP_MEMORY_SCOPE_AGENT);
                while (__hip_atomic_fetch_add(mybar, 0u, __ATOMIC_RELAXED, __HIP_MEMORY_SCOPE_AGENT)
                       < 8u * (unsigned)(t + 2))
                    __builtin_amdgcn_s_sleep(1);
            }
            __syncthreads();                           // whole block sees barrier passed
            if (FAST)                                  // flash-inv per-CU L1 (h lines may be stale)
                asm volatile("buffer_inv sc0" ::: "memory");
        } else {
            // final step: plain-layout hfin (kernel-boundary coherence for head)
#pragma unroll
            for (int m = 0; m < 4; ++m) {
                float4 bb = bq[m];
#pragma unroll
                for (int nf = 0; nf < 5; ++nf) {
                    f32x4 g = acc[m][nf];
                    float gi = fsig(g[0] + bb.x);
                    float gf = fsig(g[1] + bb.y);
                    float gz = ftanh(g[2] + bb.z);
                    float go = fsig(g[3] + bb.w);
                    float cn = gf * c4[nf][m] + gi * gz;
                    float hn = go * ftanh(cn);
                    int col = bgrp * TILE + nw * 80 + nf * 16 + lr;
                    int hid = msub * 32 + mw * 16 + m * 4 + lq;
                    hfin[((size_t)dir * NB + col) * HSZ + hid] = (bf16_t)hn;
                }
            }
        }
    }
}

// ---- persistent LSTM: XCD-verified fast exchange -------------------------
// 256 blocks x 512 thr, 1 block/CU. bid = msub*32 + dir*16 + bgrp; the 8
// group members share bid%8 -> one XCD under round-robin. Verified at
// runtime via HW_REG_XCC_ID; mismatch -> r12-proven coherent slow path.
__global__ __launch_bounds__(512, 1)
void lstm_persist(const bf16_t* __restrict__ Wf, const float* __restrict__ bias,
                  const bf16_t* __restrict__ xBf, const float* __restrict__ cws,
                  bf16_t* __restrict__ hA, bf16_t* __restrict__ hB,
                  bf16_t* __restrict__ hfin, unsigned* __restrict__ bar,
                  unsigned* __restrict__ xccA)
{
    __shared__ __align__(16) bf16_t wL[8 * 12 * 512];  // 96KB W slice
    __shared__ __align__(16) bf16_t pkL[CH];           // 20KB h pack buffer
    __shared__ int sFast;

    const int bid  = blockIdx.x;
    const int msub = bid >> 5;
    const int dir  = (bid >> 4) & 1;
    const int bgrp = bid & 15;
    const int tid  = threadIdx.x;
    const int lane = tid & 63;
    const int mw   = (tid >> 6) >> 2;                  // 0..1
    const int nw   = (tid >> 6) & 3;                   // 0..3
    const int lr   = lane & 15;
    const int lq   = lane >> 4;

    // --- stage W slice once; c -> registers; bias -> registers ---
    {
        const uint4* wsrc = (const uint4*)(Wf + ((size_t)dir * 64 + msub * 8) * 12 * 512);
        uint4* wdst = (uint4*)wL;
        for (int i = tid; i < 6144; i += 512) wdst[i] = wsrc[i];
    }
    const float* cp = cws + ((size_t)bid * 512 + tid) * 20;
    f32x4 c4[5];
#pragma unroll
    for (int nf = 0; nf < 5; ++nf) c4[nf] = *(const f32x4*)(cp + nf * 4);
    float4 bq[4];
#pragma unroll
    for (int m = 0; m < 4; ++m)
        bq[m] = *(const float4*)(bias + dir * G4 + (msub * 32 + mw * 16 + m * 4 + lq) * 4);

    unsigned* mybar = bar + (dir * NBGRP + bgrp) * 16; // 64B-spaced counters

    // --- publish XCD id, group-verify co-location (once) ---
    unsigned xcc;
    asm volatile("s_getreg_b32 %0, hwreg(HW_REG_XCC_ID)" : "=s"(xcc));
    if (tid == 0) {
        __hip_atomic_store(&xccA[bid], xcc, __ATOMIC_RELAXED, __HIP_MEMORY_SCOPE_AGENT);
        __hip_atomic_fetch_add(mybar, 1u, __ATOMIC_RELEASE, __HIP_MEMORY_SCOPE_AGENT);
        while (__hip_atomic_fetch_add(mybar, 0u, __ATOMIC_RELAXED, __HIP_MEMORY_SCOPE_AGENT) < 8u)
            __builtin_amdgcn_s_sleep(1);
        int ok = (xcc < 8u) ? 1 : 0;
        for (int m2 = 0; m2 < 8; ++m2) {
            unsigned v = __hip_atomic_load(&xccA[m2 * 32 + dir * 16 + bgrp],
                                           __ATOMIC_RELAXED, __HIP_MEMORY_SCOPE_AGENT);
            ok &= (v == xcc) ? 1 : 0;
        }
        sFast = ok;
    }
    __syncthreads();

    if (sFast)
        run_steps<true>(xBf, hA, hB, hfin, wL, pkL, mybar, c4, bq,
                        dir, bgrp, msub, tid, lane, mw, nw, lr, lq);
    else
        run_steps<false>(xBf, hA, hB, hfin, wL, pkL, mybar, c4, bq,
                         dir, bgrp, msub, tid, lane, mw, nw, lr, lq);
}

// ---- head: x_fea assembly + Linear(2560,64) + Linear(64,5) + softmax ----
__global__ __launch_bounds__(256)
void head_kernel(const bf16_t* __restrict__ hfin, const float* __restrict__ W1T,
                 const float* __restrict__ b1, const float* __restrict__ W2,
                 const float* __restrict__ b2, float* __restrict__ out)
{
    __shared__ float flat_s[2560];
    __shared__ float partial[4][64];
    __shared__ float zs[64];
    __shared__ float ls[5];
    __shared__ float es[5];
    int b = blockIdx.x, tid = threadIdx.x;
    const bf16_t* hF = hfin;
    const bf16_t* hB = hfin + (size_t)NB * HSZ;
    float* xfea = out + BATCH * 5 + (size_t)b * 2560;

    for (int j = tid; j < 2560; j += 256) {
        int s = j >> 8, c = j & 255;
        int n = b * 10 + s;
        float v = (c < 128) ? (float)hF[(size_t)n * HSZ + c] : (float)hB[(size_t)n * HSZ + c];
        flat_s[j] = v;
        xfea[j] = v;
    }
    __syncthreads();
    int j = tid & 63, q = tid >> 6;
    float sum = 0.0f;
    for (int k = q * 640; k < (q + 1) * 640; ++k) sum += flat_s[k] * W1T[k * 64 + j];
    partial[q][j] = sum;
    __syncthreads();
    if (tid < 64) zs[tid] = partial[0][tid] + partial[1][tid] + partial[2][tid] + partial[3][tid] + b1[tid];
    __syncthreads();
    if (tid < 5) {
        float l = b2[tid];
        for (int k = 0; k < 64; ++k) l += zs[k] * W2[tid * 64 + k];
        ls[tid] = l;
    }
    __syncthreads();
    if (tid < 5) {
        float m = ls[0];
        for (int k = 1; k < 5; ++k) m = fmaxf(m, ls[k]);
        es[tid] = __expf(ls[tid] - m);
    }
    __syncthreads();
    if (tid < 5) {
        float s5 = es[0] + es[1] + es[2] + es[3] + es[4];
        out[b * 5 + tid] = es[tid] / s5;
    }
}

extern "C" void kernel_launch(void* const* d_in, const int* in_sizes, int n_in,
                              void* d_out, int out_size, void* d_ws, size_t ws_size,
                              hipStream_t stream) {
    const float* x     = (const float*)d_in[0];
    const float* h0    = (const float*)d_in[1];
    const float* c0    = (const float*)d_in[2];
    const float* Wih_f = (const float*)d_in[3];
    const float* Whh_f = (const float*)d_in[4];
    const float* bih_f = (const float*)d_in[5];
    const float* bhh_f = (const float*)d_in[6];
    const float* Wih_b = (const float*)d_in[7];
    const float* Whh_b = (const float*)d_in[8];
    const float* bih_b = (const float*)d_in[9];
    const float* bhh_b = (const float*)d_in[10];
    const float* W1    = (const float*)d_in[11];
    const float* b1    = (const float*)d_in[12];
    const float* W2    = (const float*)d_in[13];
    const float* b2    = (const float*)d_in[14];
    float* out = (float*)d_out;

    uintptr_t ws = (uintptr_t)d_ws;
    bf16_t*   Wf   = (bf16_t*)(ws);                    // 1,572,864
    float*    bias = (float*)(ws + 1572864);           // 8,192
    bf16_t*   xBf  = (bf16_t*)(ws + 1581056);          // 39,321,600
    bf16_t*   hAb  = (bf16_t*)(ws + 40902656);         // 5,242,880
    bf16_t*   hBb  = (bf16_t*)(ws + 46145536);         // 5,242,880
    bf16_t*   hfin = (bf16_t*)(ws + 51388416);         // 5,242,880
    float*    W1T  = (float*)(ws + 56631296);          // 655,360
    float*    cws  = (float*)(ws + 57286656);          // 10,485,760
    unsigned* bar  = (unsigned*)(ws + 67772416);       // 2,048 (32 groups x 64B)
    unsigned* xccA = (unsigned*)(ws + 67774464);       // 1,024 (256 u32)

    hipMemsetAsync((void*)bar, 0, 4096, stream);

    prep_weights<<<(2 * G4 * 384 + 255) / 256, 256, 0, stream>>>(
        Wih_f, Whh_f, bih_f, bhh_f, Wih_b, Whh_b, bih_b, bhh_b, Wf, bias);
    prep_x<<<(NBGRP * TSEQ * SLABX + 255) / 256, 256, 0, stream>>>(x, xBf);
    prep_state<<<(2 * NBGRP * SLABH + 255) / 256, 256, 0, stream>>>(h0, hAb);
    prep_c<<<(256 * 512 * 20 + 255) / 256, 256, 0, stream>>>(c0, cws);
    prep_w1t<<<(2560 * 64 + 255) / 256, 256, 0, stream>>>(W1, W1T);

    lstm_persist<<<256, 512, 0, stream>>>(Wf, bias, xBf, cws, hAb, hBb, hfin, bar, xccA);
    head_kernel<<<BATCH, 256, 0, stream>>>(hfin, W1T, b1, W2, b2, out);
}